// Round 9
// baseline (223.797 us; speedup 1.0000x reference)
//
#include <hip/hip_runtime.h>

// ---------------------------------------------------------------------------
// Geometry: b=64, units=32, d_model=4096, P=16 -> c=2, d=256, C=512,
// dwconv 3x3 s2 16x16->8x8 (hw=64), dk=64; attn 256x256 per (b,cc).
//
// KEY RESTRUCTURING: conv1d (16->32ch) and Linear (over l) commute:
//   out = c1w · (X · W^T) + c1b · rowsum(W) + lin_b
// so the big GEMM runs at M=1024 (X rows) instead of M=2048 -> half FLOPs.
//
// All GEMM-shaped work runs as bf16 hi/lo split MFMA:
//   C = Ah*Bh + Ah*Bl + Al*Bh  (K' = 3K, error ~2^-17 rel).
//
// Workspace (ws = 48 MiB) / d_out (32 MiB) choreography:
//   phase1: qp @ws0 (8.4M), kpp @8.4M, vtp @16.8M, tTp @25.2M (25.2M)
//           pwkp -> d_out[0..3.1M] (d_out dead)
//   attn  : Xp split-bf16 [1024][4096] @ws 25.2M (tTp dead)
//   split : lwp -> d_out[0..33.5M] (pwkp dead); rs fp32[4096] @ws0 (qp dead)
//   GEMM  : G fp32 [1024][4096] @ws 33.5M..50.3M
//   epilog: reads G/rs/c1w/c1b/linb -> writes d_out (lwp dead)
// ---------------------------------------------------------------------------

typedef short s16x8 __attribute__((ext_vector_type(8)));
typedef float f32x4 __attribute__((ext_vector_type(4)));
typedef const __attribute__((address_space(1))) void* gas_t;
typedef __attribute__((address_space(3))) void* las_t;

__device__ __forceinline__ unsigned short f2bf(float x) {
  unsigned u = __float_as_uint(x);
  unsigned r = u + 0x7fffu + ((u >> 16) & 1u);
  return (unsigned short)(r >> 16);
}
__device__ __forceinline__ float bf2f(unsigned short h) {
  return __uint_as_float((unsigned)h << 16);
}

// ======================= Stage A: patch + dwconv + BN + GELU (batched) =====
__global__ __launch_bounds__(256) void stageA_kernel(
    const float* __restrict__ xq, const float* __restrict__ xk,
    const float* __restrict__ xv, const float* __restrict__ dwk,
    const float* __restrict__ bng, const float* __restrict__ bnb,
    const float* __restrict__ bnm, const float* __restrict__ bnv,
    unsigned short* __restrict__ tTp)
{
  const int i  = blockIdx.y;
  const float* x = (i == 0) ? xq : (i == 1) ? xk : xv;
  const float* dwk_i = dwk + (size_t)i * 4608;
  const int co = i * 512;
  unsigned short* out = tTp + (size_t)i * 4194304;

  const int dd = threadIdx.x;
  const int oh = blockIdx.x & 7;
  const int cc = (blockIdx.x >> 3) & 1;
  const int b  = blockIdx.x >> 4;
  const int ch = cc * 256 + dd;

  float r[3][16];
#pragma unroll
  for (int kh = 0; kh < 3; ++kh) {
    int ih = 2 * oh - 1 + kh;
    if (ih >= 0 && ih <= 15) {
      const float* p = x + (size_t)(b * 32 + cc * 16 + ih) * 4096 + dd * 16;
#pragma unroll
      for (int jq = 0; jq < 4; ++jq)
        *(float4*)&r[kh][jq * 4] = *(const float4*)(p + jq * 4);
    } else {
#pragma unroll
      for (int j = 0; j < 16; ++j) r[kh][j] = 0.f;
    }
  }
  float w9[9];
#pragma unroll
  for (int j = 0; j < 9; ++j) w9[j] = dwk_i[ch * 9 + j];
  const float scale = bng[co + ch] / sqrtf(bnv[co + ch] + 1e-5f);
  const float shift = bnb[co + ch] - bnm[co + ch] * scale;

#pragma unroll
  for (int ow = 0; ow < 8; ++ow) {
    float acc = 0.f;
#pragma unroll
    for (int kh = 0; kh < 3; ++kh)
#pragma unroll
      for (int kw = 0; kw < 3; ++kw) {
        int iw = 2 * ow - 1 + kw;
        if (iw >= 0 && iw <= 15) acc = fmaf(r[kh][iw], w9[kh * 3 + kw], acc);
      }
    float y = acc * scale + shift;
    y = 0.5f * y * (1.f + erff(y * 0.70710678118654752f));
    unsigned short hi = f2bf(y);
    unsigned short lo = f2bf(y - bf2f(hi));
    size_t rowb = (size_t)(b * 64 + oh * 8 + ow) * 1024;
    out[rowb + ch] = hi;
    out[rowb + 512 + ch] = lo;
  }
}

// ======================= fp32 -> bf16 hi|lo split ==========================
__global__ __launch_bounds__(256) void split_kernel(
    const float* __restrict__ src, unsigned short* __restrict__ dst,
    int kshift, int total4)
{
  int i = blockIdx.x * 256 + threadIdx.x;
  if (i >= total4) return;
  size_t i4 = (size_t)i * 4;
  int K = 1 << kshift;
  int r = (int)(i4 >> kshift);
  int c = (int)(i4 & (size_t)(K - 1));
  float4 xv = *(const float4*)(src + i4);
  unsigned short h0 = f2bf(xv.x), h1 = f2bf(xv.y), h2 = f2bf(xv.z), h3 = f2bf(xv.w);
  unsigned short l0 = f2bf(xv.x - bf2f(h0)), l1 = f2bf(xv.y - bf2f(h1));
  unsigned short l2 = f2bf(xv.z - bf2f(h2)), l3 = f2bf(xv.w - bf2f(h3));
  unsigned short* dr = dst + (size_t)r * (K * 2) + c;
  uint2 hp, lp;
  hp.x = (unsigned)h0 | ((unsigned)h1 << 16);
  hp.y = (unsigned)h2 | ((unsigned)h3 << 16);
  lp.x = (unsigned)l0 | ((unsigned)l1 << 16);
  lp.y = (unsigned)l2 | ((unsigned)l3 << 16);
  *(uint2*)dr = hp;
  *(uint2*)(dr + K) = lp;
}

// ======================= split + row-sum (for linw) ========================
__global__ __launch_bounds__(256) void split_rs_kernel(
    const float* __restrict__ src, unsigned short* __restrict__ dst,
    float* __restrict__ rs, int total4)
{
  int i = blockIdx.x * 256 + threadIdx.x;
  if (i >= total4) return;
  size_t i4 = (size_t)i * 4;
  int r = (int)(i4 >> 11);
  int c = (int)(i4 & 2047);
  float4 xv = *(const float4*)(src + i4);
  unsigned short h0 = f2bf(xv.x), h1 = f2bf(xv.y), h2 = f2bf(xv.z), h3 = f2bf(xv.w);
  unsigned short l0 = f2bf(xv.x - bf2f(h0)), l1 = f2bf(xv.y - bf2f(h1));
  unsigned short l2 = f2bf(xv.z - bf2f(h2)), l3 = f2bf(xv.w - bf2f(h3));
  unsigned short* dr = dst + (size_t)r * 4096 + c;
  uint2 hp, lp;
  hp.x = (unsigned)h0 | ((unsigned)h1 << 16);
  hp.y = (unsigned)h2 | ((unsigned)h3 << 16);
  lp.x = (unsigned)l0 | ((unsigned)l1 << 16);
  lp.y = (unsigned)l2 | ((unsigned)l3 << 16);
  *(uint2*)dr = hp;
  *(uint2*)(dr + 2048) = lp;
  // all 64 lanes of a wave lie in the same row r (waves 256-elem aligned)
  float s = xv.x + xv.y + xv.z + xv.w;
#pragma unroll
  for (int off = 1; off < 64; off <<= 1) s += __shfl_xor(s, off, 64);
  if ((threadIdx.x & 63) == 0) atomicAdd(&rs[r], s);
}

// ======================= pointwise: bf16-split MFMA NT GEMM (batched z=3) ==
__global__ __launch_bounds__(256) void gemm_split_kernel(
    const unsigned short* __restrict__ Aall, const unsigned short* __restrict__ Ball,
    unsigned short* __restrict__ Call, int M, int N, int K)
{
  __shared__ unsigned short sA[4096];    // [64][64]
  __shared__ unsigned short sB[8192];    // [128][64]
  const int t = threadIdx.x;
  const int z = blockIdx.z;
  const unsigned short* A = Aall + (size_t)z * 524288;
  const unsigned short* B = Ball + (size_t)z * 4194304;
  unsigned short* Cq = Call + (size_t)z * 4194304;
  const int m0 = blockIdx.y * 64, n0 = blockIdx.x * 128;
  const int Kp = 3 * K, twoK = 2 * K, Km = K - 1;
  const int lane = t & 63;
  const int wv = t >> 6;
  const int colbase = wv * 32;
  const int h = lane & 15, g = lane >> 4;

  f32x4 acc[4][2];
#pragma unroll
  for (int mf = 0; mf < 4; ++mf)
#pragma unroll
    for (int nf = 0; nf < 2; ++nf)
      acc[mf][nf] = (f32x4){0.f, 0.f, 0.f, 0.f};

  int srow[4], sblk[4];
#pragma unroll
  for (int it = 0; it < 4; ++it) {
    int s = it * 256 + t;
    srow[it] = s >> 3;
    sblk[it] = (s & 7) ^ (srow[it] & 7);
  }
  const int ldsw = (t & 192) << 4;

  for (int k0 = 0; k0 < Kp; k0 += 64) {
    __syncthreads();
#pragma unroll
    for (int it = 0; it < 2; ++it) {
      int kp = k0 + sblk[it] * 8;
      int ac = (kp < twoK) ? (kp & Km) : (kp - K);
      const unsigned short* ga = A + (size_t)(m0 + srow[it]) * twoK + ac;
      __builtin_amdgcn_global_load_lds((gas_t)(const void*)ga,
          (las_t)(void*)((char*)sA + (it * 4096 + ldsw)), 16, 0, 0);
    }
#pragma unroll
    for (int it = 0; it < 4; ++it) {
      int kp = k0 + sblk[it] * 8;
      int bc = (kp < twoK) ? kp : (kp - twoK);
      const unsigned short* gb = B + (size_t)(n0 + srow[it]) * twoK + bc;
      __builtin_amdgcn_global_load_lds((gas_t)(const void*)gb,
          (las_t)(void*)((char*)sB + (it * 4096 + ldsw)), 16, 0, 0);
    }
    __syncthreads();

#pragma unroll
    for (int kk = 0; kk < 2; ++kk) {
      s16x8 af[4], bfr[2];
#pragma unroll
      for (int mf = 0; mf < 4; ++mf) {
        int arow = mf * 16 + h;
        int aoff = arow * 128 + (((kk * 4 + g) ^ (h & 7)) << 4);
        af[mf] = *(const s16x8*)((const char*)sA + aoff);
      }
#pragma unroll
      for (int nf = 0; nf < 2; ++nf) {
        int brow = colbase + nf * 16 + h;
        int boff = brow * 128 + (((kk * 4 + g) ^ (h & 7)) << 4);
        bfr[nf] = *(const s16x8*)((const char*)sB + boff);
      }
#pragma unroll
      for (int mf = 0; mf < 4; ++mf)
#pragma unroll
        for (int nf = 0; nf < 2; ++nf)
          acc[mf][nf] = __builtin_amdgcn_mfma_f32_16x16x32_bf16(
              af[mf], bfr[nf], acc[mf][nf], 0, 0, 0);
    }
  }

  if (z < 2) {
    // Q'/K' layout: rows = attention row index (ch%256), cols = d hi|lo
#pragma unroll
    for (int mf = 0; mf < 4; ++mf) {
      int mbase = m0 + mf * 16 + g * 4;
#pragma unroll
      for (int nf = 0; nf < 2; ++nf) {
        int n = n0 + colbase + nf * 16 + h;
        int bb = n >> 6, d = n & 63;
#pragma unroll
        for (int qq = 0; qq < 4; ++qq) {
          int m = mbase + qq;
          int cc = m >> 8;
          size_t rowb = ((size_t)(bb * 2 + cc) * 256 + (m & 255)) * 128;
          float vvv = acc[mf][nf][qq];
          unsigned short hi = f2bf(vvv);
          unsigned short lo = f2bf(vvv - bf2f(hi));
          Cq[rowb + d] = hi;
          Cq[rowb + 64 + d] = lo;
        }
      }
    }
  } else {
    // V^T layout: rows = d, cols = j hi|lo
#pragma unroll
    for (int mf = 0; mf < 4; ++mf) {
      int mbase = m0 + mf * 16 + g * 4;
      int cc = mbase >> 8;
      int mc = mbase & 255;
#pragma unroll
      for (int nf = 0; nf < 2; ++nf) {
        int n = n0 + colbase + nf * 16 + h;
        int bb = n >> 6, d = n & 63;
        size_t rowb = ((size_t)(bb * 2 + cc) * 64 + d) * 512;
        ushort4 hv, lv;
        float v0 = acc[mf][nf][0], v1 = acc[mf][nf][1];
        float v2 = acc[mf][nf][2], v3 = acc[mf][nf][3];
        hv.x = f2bf(v0); hv.y = f2bf(v1); hv.z = f2bf(v2); hv.w = f2bf(v3);
        lv.x = f2bf(v0 - bf2f(hv.x)); lv.y = f2bf(v1 - bf2f(hv.y));
        lv.z = f2bf(v2 - bf2f(hv.z)); lv.w = f2bf(v3 - bf2f(hv.w));
        *(ushort4*)&Cq[rowb + mc] = hv;
        *(ushort4*)&Cq[rowb + 256 + mc] = lv;
      }
    }
  }
}

// ======================= final GEMM: G = X' * lwp^T (pipelined) ============
// BM=64, BN=128, BK=64, 4 waves (1x4), 3 LDS buffers (72 KB -> 2 blocks/CU),
// counted vmcnt(6). Grid (32,16) ONLY (hardcoded swizzle).
__global__ __launch_bounds__(256, 2) void gemm_final_kernel(
    const unsigned short* __restrict__ A, const unsigned short* __restrict__ B,
    float* __restrict__ C, int M, int N, int K)
{
  __shared__ unsigned short lds[36864];    // 73728 B = 3 x 24576
  const int t = threadIdx.x;

  // XCD swizzle: 512 blocks, contiguous chunk of 64 per XCD
  const int flat = blockIdx.y * 32 + blockIdx.x;
  const int swz = (flat & 7) * 64 + (flat >> 3);
  const int n0 = (swz & 31) * 128;
  const int m0 = (swz >> 5) * 64;

  const int twoK = 2 * K, Km = K - 1;
  const int nt = (3 * K) >> 6;             // 96 K-tiles

  const int lane = t & 63;
  const int wv = t >> 6;
  const int colbase = wv * 32;
  const int h = lane & 15, g = lane >> 4;

  f32x4 acc[4][2];
#pragma unroll
  for (int mf = 0; mf < 4; ++mf)
#pragma unroll
    for (int nf = 0; nf < 2; ++nf)
      acc[mf][nf] = (f32x4){0.f, 0.f, 0.f, 0.f};

  int arow[2], ablk[2], brow[4], bblk[4];
#pragma unroll
  for (int it = 0; it < 2; ++it) {
    int s = it * 256 + t;
    arow[it] = s >> 3;
    ablk[it] = (s & 7) ^ (arow[it] & 7);
  }
#pragma unroll
  for (int it = 0; it < 4; ++it) {
    int s = it * 256 + t;
    brow[it] = s >> 3;
    bblk[it] = (s & 7) ^ (brow[it] & 7);
  }

  auto issueA = [&](int buf, int tt, int it) {
    int kp = tt * 64 + ablk[it] * 8;
    int ac = (kp < twoK) ? (kp & Km) : (kp - K);
    __builtin_amdgcn_global_load_lds(
        (gas_t)(const void*)(A + (size_t)(m0 + arow[it]) * twoK + ac),
        (las_t)(void*)((char*)lds + (buf * 24576 + it * 4096 + t * 16)), 16, 0, 0);
  };
  auto issueB = [&](int buf, int tt, int it) {
    int kp = tt * 64 + bblk[it] * 8;
    int bc = (kp < twoK) ? kp : (kp - twoK);
    __builtin_amdgcn_global_load_lds(
        (gas_t)(const void*)(B + (size_t)(n0 + brow[it]) * twoK + bc),
        (las_t)(void*)((char*)lds + (buf * 24576 + 8192 + it * 4096 + t * 16)), 16, 0, 0);
  };

  int colx[2];
  colx[0] = ((g) ^ (h & 7)) << 4;
  colx[1] = ((4 + g) ^ (h & 7)) << 4;

  auto rdA = [&](int buf, int kk, int mf) -> s16x8 {
    return *(const s16x8*)((const char*)lds +
        (buf * 24576 + (mf * 16 + h) * 128 + colx[kk]));
  };
  auto rdB = [&](int buf, int kk, int nf) -> s16x8 {
    return *(const s16x8*)((const char*)lds +
        (buf * 24576 + 8192 + (colbase + nf * 16 + h) * 128 + colx[kk]));
  };

#define MFMA8(A0, A1, A2, A3, B0, B1) \
  acc[0][0] = __builtin_amdgcn_mfma_f32_16x16x32_bf16(A0, B0, acc[0][0], 0, 0, 0); \
  acc[1][0] = __builtin_amdgcn_mfma_f32_16x16x32_bf16(A1, B0, acc[1][0], 0, 0, 0); \
  acc[2][0] = __builtin_amdgcn_mfma_f32_16x16x32_bf16(A2, B0, acc[2][0], 0, 0, 0); \
  acc[3][0] = __builtin_amdgcn_mfma_f32_16x16x32_bf16(A3, B0, acc[3][0], 0, 0, 0); \
  acc[0][1] = __builtin_amdgcn_mfma_f32_16x16x32_bf16(A0, B1, acc[0][1], 0, 0, 0); \
  acc[1][1] = __builtin_amdgcn_mfma_f32_16x16x32_bf16(A1, B1, acc[1][1], 0, 0, 0); \
  acc[2][1] = __builtin_amdgcn_mfma_f32_16x16x32_bf16(A2, B1, acc[2][1], 0, 0, 0); \
  acc[3][1] = __builtin_amdgcn_mfma_f32_16x16x32_bf16(A3, B1, acc[3][1], 0, 0, 0);

  // ---- prologue: stage tiles 0 and 1 (6 loads each) ----
#pragma unroll
  for (int it = 0; it < 2; ++it) issueA(0, 0, it);
#pragma unroll
  for (int it = 0; it < 4; ++it) issueB(0, 0, it);
#pragma unroll
  for (int it = 0; it < 2; ++it) issueA(1, 1, it);
#pragma unroll
  for (int it = 0; it < 4; ++it) issueB(1, 1, it);
  asm volatile("s_waitcnt vmcnt(6)" ::: "memory");
  __builtin_amdgcn_sched_barrier(0);
  __builtin_amdgcn_s_barrier();
  __builtin_amdgcn_sched_barrier(0);

  int bR = 0;
  for (int tt = 0; tt <= nt - 3; ++tt) {
    const int bn2 = (bR >= 1) ? bR - 1 : 2;      // (bR+2)%3
    // ---- phase 0 (kk=0): 6 ds_read; prefetch A0,A1,B0 ----
    s16x8 a0 = rdA(bR, 0, 0), a1 = rdA(bR, 0, 1), a2 = rdA(bR, 0, 2), a3 = rdA(bR, 0, 3);
    s16x8 b0 = rdB(bR, 0, 0), b1 = rdB(bR, 0, 1);
    issueA(bn2, tt + 2, 0); issueA(bn2, tt + 2, 1); issueB(bn2, tt + 2, 0);
    __builtin_amdgcn_s_barrier();
    __builtin_amdgcn_s_setprio(1);
    MFMA8(a0, a1, a2, a3, b0, b1)
    __builtin_amdgcn_s_setprio(0);
    __builtin_amdgcn_s_barrier();
    // ---- phase 1 (kk=1): 6 ds_read; prefetch B1..B3; counted vmcnt ----
    a0 = rdA(bR, 1, 0); a1 = rdA(bR, 1, 1); a2 = rdA(bR, 1, 2); a3 = rdA(bR, 1, 3);
    b0 = rdB(bR, 1, 0); b1 = rdB(bR, 1, 1);
    issueB(bn2, tt + 2, 1); issueB(bn2, tt + 2, 2); issueB(bn2, tt + 2, 3);
    __builtin_amdgcn_s_barrier();
    __builtin_amdgcn_s_setprio(1);
    MFMA8(a0, a1, a2, a3, b0, b1)
    __builtin_amdgcn_s_setprio(0);
    asm volatile("s_waitcnt vmcnt(6)" ::: "memory");
    __builtin_amdgcn_sched_barrier(0);
    __builtin_amdgcn_s_barrier();
    __builtin_amdgcn_sched_barrier(0);
    bR = (bR == 2) ? 0 : bR + 1;
  }

  auto compute_tile = [&](int buf) {
#pragma unroll
    for (int kk = 0; kk < 2; ++kk) {
      s16x8 ta0 = rdA(buf, kk, 0), ta1 = rdA(buf, kk, 1);
      s16x8 ta2 = rdA(buf, kk, 2), ta3 = rdA(buf, kk, 3);
      s16x8 tb0 = rdB(buf, kk, 0), tb1 = rdB(buf, kk, 1);
      MFMA8(ta0, ta1, ta2, ta3, tb0, tb1)
    }
  };
  compute_tile(bR);
  __syncthreads();
  compute_tile((bR == 2) ? 0 : bR + 1);
#undef MFMA8

#pragma unroll
  for (int mf = 0; mf < 4; ++mf) {
    int mbase = m0 + mf * 16 + g * 4;
#pragma unroll
    for (int nf = 0; nf < 2; ++nf) {
      int n = n0 + colbase + nf * 16 + h;
#pragma unroll
      for (int qq = 0; qq < 4; ++qq)
        C[(size_t)(mbase + qq) * N + n] = acc[mf][nf][qq];
    }
  }
}

// ======================= Attention (MFMA, split bf16) ======================
// Writes O directly as X' split-bf16 [1024][4096] (GEMM-A layout):
//   Xrow = b*16 + cc*8 + (d>>3), Xcol = dd*8 + (d&7), lo at +2048.
__global__ __launch_bounds__(256) void attn_mfma_kernel(
    const unsigned short* __restrict__ qp, const unsigned short* __restrict__ kp,
    const unsigned short* __restrict__ vtp, const float* __restrict__ pos,
    unsigned short* __restrict__ Xp)
{
  __shared__ char smem[59904];
  unsigned short* qs = (unsigned short*)smem;
  unsigned short* kv = (unsigned short*)(smem + 8704);
  float* sc = (float*)(smem + 26112);
  unsigned short* ps = (unsigned short*)(smem + 26112);

  const int t = threadIdx.x;
  const int rt = blockIdx.x, cc = blockIdx.y, b = blockIdx.z;
  const int i0 = rt * 32;
  const size_t qkbase = (size_t)(b * 2 + cc) * 256;
  const size_t vbase  = (size_t)(b * 2 + cc) * 64;

  const int lane = t & 63, wvv = t >> 6;
  const int h = lane & 15, g = lane >> 4;

  // ---- stage Q tile (32 rows x 128 split cols = 512 int4) ----
#pragma unroll
  for (int rep = 0; rep < 2; ++rep) {
    int s = t + rep * 256;
    int row = s >> 4;
    int blk = s & 15;
    int4 val = *(const int4*)(qp + (qkbase + i0 + row) * 128 + blk * 8);
    *(int4*)((char*)qs + row * 272 + blk * 16) = val;
  }

  // ---- S phase: 4 chunks of 64 cols ----
  for (int c = 0; c < 4; ++c) {
    __syncthreads();
#pragma unroll
    for (int p2 = 0; p2 < 4; ++p2) {
      int s = t + p2 * 256;
      int row = s >> 4;
      int blk = s & 15;
      int4 val = *(const int4*)(kp + (qkbase + c * 64 + row) * 128 + blk * 8);
      *(int4*)((char*)kv + row * 272 + blk * 16) = val;
    }
    __syncthreads();
    f32x4 acc2[2];
    acc2[0] = (f32x4){0.f, 0.f, 0.f, 0.f};
    acc2[1] = (f32x4){0.f, 0.f, 0.f, 0.f};
#pragma unroll
    for (int kk = 0; kk < 6; ++kk) {
      int abase = (kk < 2) ? kk * 32 : (kk < 4) ? 64 + (kk - 2) * 32 : (kk - 4) * 32;
      int bbase = (kk < 2) ? kk * 32 : (kk < 4) ? (kk - 2) * 32 : 64 + (kk - 4) * 32;
      s16x8 bfrag = *(const s16x8*)((char*)kv + (wvv * 16 + h) * 272 + (bbase + g * 8) * 2);
#pragma unroll
      for (int mf = 0; mf < 2; ++mf) {
        s16x8 afrag = *(const s16x8*)((char*)qs + (mf * 16 + h) * 272 + (abase + g * 8) * 2);
        acc2[mf] = __builtin_amdgcn_mfma_f32_16x16x32_bf16(afrag, bfrag, acc2[mf], 0, 0, 0);
      }
    }
#pragma unroll
    for (int mf = 0; mf < 2; ++mf)
#pragma unroll
      for (int qq = 0; qq < 4; ++qq) {
        int row = mf * 16 + g * 4 + qq;
        int j = c * 64 + wvv * 16 + h;
        sc[row * 264 + j] = acc2[mf][qq] * 0.125f +
            pos[((size_t)cc * 256 + i0 + row) * 256 + j];
      }
  }
  __syncthreads();

  // ---- softmax + in-place P split-bf16 ----
  {
    const int r = t >> 3, j8 = t & 7;
    float e[32];
    float mx = -3.4e38f;
#pragma unroll
    for (int jj = 0; jj < 32; ++jj) {
      e[jj] = sc[r * 264 + j8 + 8 * jj];
      mx = fmaxf(mx, e[jj]);
    }
#pragma unroll
    for (int mset = 1; mset < 8; mset <<= 1) mx = fmaxf(mx, __shfl_xor(mx, mset, 64));
    float sum = 0.f;
#pragma unroll
    for (int jj = 0; jj < 32; ++jj) {
      e[jj] = expf(e[jj] - mx);
      sum += e[jj];
    }
#pragma unroll
    for (int mset = 1; mset < 8; mset <<= 1) sum += __shfl_xor(sum, mset, 64);
    float inv = 1.f / sum;
    __syncthreads();
#pragma unroll
    for (int jj = 0; jj < 32; ++jj) {
      float pv = e[jj] * inv;
      unsigned short hi = f2bf(pv);
      unsigned short lo = f2bf(pv - bf2f(hi));
      int j = j8 + 8 * jj;
      ps[r * 528 + j] = hi;
      ps[r * 528 + 264 + j] = lo;
    }
  }

  // ---- PV ----
  f32x4 oacc[2];
  oacc[0] = (f32x4){0.f, 0.f, 0.f, 0.f};
  oacc[1] = (f32x4){0.f, 0.f, 0.f, 0.f};
  for (int c = 0; c < 4; ++c) {
    __syncthreads();
#pragma unroll
    for (int p2 = 0; p2 < 4; ++p2) {
      int s = t + p2 * 256, row = s >> 4, blk = s & 15;
      int col = (blk < 8) ? (c * 64 + blk * 8) : (256 + c * 64 + (blk - 8) * 8);
      int4 val = *(const int4*)(vtp + (vbase + row) * 512 + col);
      *(int4*)((char*)kv + row * 272 + blk * 16) = val;
    }
    __syncthreads();
#pragma unroll
    for (int kk = 0; kk < 6; ++kk) {
      int abase = (kk < 2) ? (c * 64 + kk * 32)
                : (kk < 4) ? (264 + c * 64 + (kk - 2) * 32)
                           : (c * 64 + (kk - 4) * 32);
      int bbase = (kk < 2) ? kk * 32 : (kk < 4) ? (kk - 2) * 32 : 64 + (kk - 4) * 32;
      s16x8 bfrag = *(const s16x8*)((char*)kv + (wvv * 16 + h) * 272 + (bbase + g * 8) * 2);
#pragma unroll
      for (int mf = 0; mf < 2; ++mf) {
        s16x8 afrag = *(const s16x8*)((char*)ps + (mf * 16 + h) * 1056 + (abase + g * 8) * 2);
        oacc[mf] = __builtin_amdgcn_mfma_f32_16x16x32_bf16(afrag, bfrag, oacc[mf], 0, 0, 0);
      }
    }
  }
  // ---- write O as X' split-bf16 ----
  {
    int Xrow = b * 16 + cc * 8 + wvv * 2 + (h >> 3);
    int c7 = h & 7;
#pragma unroll
    for (int mf = 0; mf < 2; ++mf)
#pragma unroll
      for (int qq = 0; qq < 4; ++qq) {
        int dd = i0 + mf * 16 + g * 4 + qq;
        float vvv = oacc[mf][qq];
        unsigned short hi = f2bf(vvv);
        unsigned short lo = f2bf(vvv - bf2f(hi));
        size_t base = (size_t)Xrow * 4096 + dd * 8 + c7;
        Xp[base] = hi;
        Xp[base + 2048] = lo;
      }
  }
}

// ======================= epilogue: out = c1w*G + c1b*rs + lin_b ===========
__global__ __launch_bounds__(256) void epilogue_kernel(
    const float* __restrict__ G, const float* __restrict__ rs,
    const float* __restrict__ c1w, const float* __restrict__ c1b,
    const float* __restrict__ linb, float* __restrict__ out)
{
  __shared__ float W[512];
  __shared__ float Bp[32];
  const int t = threadIdx.x;
  const int ntile = blockIdx.x;   // 0..15
  const int b = blockIdx.y;       // 0..63
  W[t] = c1w[t];                  // 256 threads: stage 2 elements each
  W[t + 256] = c1w[t + 256];
  if (t < 32) Bp[t] = c1b[t];
  __syncthreads();
  const int n = ntile * 256 + t;
  float gv[16];
#pragma unroll
  for (int ch = 0; ch < 16; ++ch)
    gv[ch] = G[(size_t)(b * 16 + ch) * 4096 + n];
  const float rsn = rs[n];
  const float lbn = linb[n];
#pragma unroll
  for (int o = 0; o < 32; ++o) {
    float s = lbn + Bp[o] * rsn;
#pragma unroll
    for (int ch = 0; ch < 16; ++ch) s = fmaf(W[o * 16 + ch], gv[ch], s);
    out[(size_t)(b * 32 + o) * 4096 + n] = s;
  }
}

// ======================= launch ============================================
extern "C" void kernel_launch(void* const* d_in, const int* in_sizes, int n_in,
                              void* d_out, int out_size, void* d_ws, size_t ws_size,
                              hipStream_t stream) {
  const float* q    = (const float*)d_in[0];
  const float* k    = (const float*)d_in[1];
  const float* v    = (const float*)d_in[2];
  const float* dwk  = (const float*)d_in[3];
  const float* bng  = (const float*)d_in[4];
  const float* bnb  = (const float*)d_in[5];
  const float* bnm  = (const float*)d_in[6];
  const float* bnv  = (const float*)d_in[7];
  const float* pwk  = (const float*)d_in[8];
  const float* pos  = (const float*)d_in[9];
  const float* c1w  = (const float*)d_in[10];
  const float* c1b  = (const float*)d_in[11];
  const float* linw = (const float*)d_in[12];
  const float* linb = (const float*)d_in[13];
  float* out = (float*)d_out;

  if (ws_size < 50331648u) return;

  char* ws = (char*)d_ws;
  unsigned short* qp   = (unsigned short*)(ws + 0);          //  8,388,608
  unsigned short* kpp  = (unsigned short*)(ws + 8388608);    //  8,388,608
  unsigned short* vtp  = (unsigned short*)(ws + 16777216);   //  8,388,608
  unsigned short* tTp  = (unsigned short*)(ws + 25165824);   // 25,165,824
  unsigned short* pwkp = (unsigned short*)d_out;             //  3,145,728 (d_out scratch)
  unsigned short* Xp   = (unsigned short*)(ws + 25165824);   //  8,388,608 (over tTp)
  float*          rs   = (float*)(ws + 0);                   //     16,384 (over qp)
  unsigned short* lwp  = (unsigned short*)d_out;             // 33,554,432 (d_out scratch)
  float*          G    = (float*)(ws + 33554432);            // 16,777,216

  // 1) split pointwise weights (into d_out scratch)
  split_kernel<<<768, 256, 0, stream>>>(pwk, pwkp, 9, 196608);

  // 2) dwconv+BN+GELU, all three inputs
  stageA_kernel<<<dim3(1024, 3), 256, 0, stream>>>(
      q, k, v, dwk, bng, bnb, bnm, bnv, tTp);

  // 3) pointwise GEMMs -> qp/kpp/vtp
  gemm_split_kernel<<<dim3(32, 8, 3), 256, 0, stream>>>(
      pwkp, tTp, qp, 512, 4096, 512);

  // 4) attention -> X' split-bf16 (GEMM-A layout)
  attn_mfma_kernel<<<dim3(8, 2, 64), 256, 0, stream>>>(qp, kpp, vtp, pos, Xp);

  // 5) split linw (+ row sums) into d_out scratch / ws
  hipMemsetAsync(rs, 0, 16384, stream);
  split_rs_kernel<<<8192, 256, 0, stream>>>(linw, lwp, rs, 2097152);

  // 6) G = X' * lwp^T   (M=1024, N=4096, K=2048 split)
  gemm_final_kernel<<<dim3(32, 16), 256, 0, stream>>>(Xp, lwp, G, 1024, 4096, 2048);

  // 7) out = c1w*G + c1b*rs + lin_b   (overwrites d_out)
  epilogue_kernel<<<dim3(16, 64), 256, 0, stream>>>(G, rs, c1w, c1b, linb, out);
}

// Round 10
// 187.794 us; speedup vs baseline: 1.1917x; 1.1917x over previous
//
#include <hip/hip_runtime.h>

// ---------------------------------------------------------------------------
// Geometry: b=64, units=32, d_model=4096, P=16 -> c=2, d=256, C=512,
// dwconv 3x3 s2 16x16->8x8 (hw=64), dk=64; attn 256x256 per (b,cc).
//
// KEY RESTRUCTURING: conv1d (16->32ch) and Linear (over l) commute:
//   out = c1w · (X · W^T) + c1b · rowsum(W) + lin_b
// so the big GEMM runs at M=1024 (X rows) instead of M=2048 -> half FLOPs.
//
// All GEMM-shaped work runs as bf16 hi/lo split MFMA:
//   C = Ah*Bh + Ah*Bl + Al*Bh  (K' = 3K, error ~2^-17 rel).
//
// Workspace (ws = 48 MiB) / d_out (32 MiB) choreography:
//   phase1: qp @ws0 (8.4M), kpp @8.4M, vtp @16.8M, tTp @25.2M (25.2M)
//           pwkp -> d_out[0..3.1M] (d_out dead)
//   attn  : Xp split-bf16 [1024][4096] @ws 25.2M (tTp dead)
//   split : lwp -> d_out[0..33.5M] (pwkp dead); rs fp32[4096] @ws0 (qp dead)
//   GEMM  : G fp32 [1024][4096] @ws 33.5M..50.3M
//   epilog: reads G/rs/c1w/c1b/linb -> writes d_out (lwp dead)
// ---------------------------------------------------------------------------

typedef short s16x8 __attribute__((ext_vector_type(8)));
typedef float f32x4 __attribute__((ext_vector_type(4)));
typedef const __attribute__((address_space(1))) void* gas_t;
typedef __attribute__((address_space(3))) void* las_t;

__device__ __forceinline__ unsigned short f2bf(float x) {
  unsigned u = __float_as_uint(x);
  unsigned r = u + 0x7fffu + ((u >> 16) & 1u);
  return (unsigned short)(r >> 16);
}
__device__ __forceinline__ float bf2f(unsigned short h) {
  return __uint_as_float((unsigned)h << 16);
}

// ======================= Stage A: patch + dwconv + BN + GELU (batched) =====
__global__ __launch_bounds__(256) void stageA_kernel(
    const float* __restrict__ xq, const float* __restrict__ xk,
    const float* __restrict__ xv, const float* __restrict__ dwk,
    const float* __restrict__ bng, const float* __restrict__ bnb,
    const float* __restrict__ bnm, const float* __restrict__ bnv,
    unsigned short* __restrict__ tTp)
{
  const int i  = blockIdx.y;
  const float* x = (i == 0) ? xq : (i == 1) ? xk : xv;
  const float* dwk_i = dwk + (size_t)i * 4608;
  const int co = i * 512;
  unsigned short* out = tTp + (size_t)i * 4194304;

  const int dd = threadIdx.x;
  const int oh = blockIdx.x & 7;
  const int cc = (blockIdx.x >> 3) & 1;
  const int b  = blockIdx.x >> 4;
  const int ch = cc * 256 + dd;

  float r[3][16];
#pragma unroll
  for (int kh = 0; kh < 3; ++kh) {
    int ih = 2 * oh - 1 + kh;
    if (ih >= 0 && ih <= 15) {
      const float* p = x + (size_t)(b * 32 + cc * 16 + ih) * 4096 + dd * 16;
#pragma unroll
      for (int jq = 0; jq < 4; ++jq)
        *(float4*)&r[kh][jq * 4] = *(const float4*)(p + jq * 4);
    } else {
#pragma unroll
      for (int j = 0; j < 16; ++j) r[kh][j] = 0.f;
    }
  }
  float w9[9];
#pragma unroll
  for (int j = 0; j < 9; ++j) w9[j] = dwk_i[ch * 9 + j];
  const float scale = bng[co + ch] / sqrtf(bnv[co + ch] + 1e-5f);
  const float shift = bnb[co + ch] - bnm[co + ch] * scale;

#pragma unroll
  for (int ow = 0; ow < 8; ++ow) {
    float acc = 0.f;
#pragma unroll
    for (int kh = 0; kh < 3; ++kh)
#pragma unroll
      for (int kw = 0; kw < 3; ++kw) {
        int iw = 2 * ow - 1 + kw;
        if (iw >= 0 && iw <= 15) acc = fmaf(r[kh][iw], w9[kh * 3 + kw], acc);
      }
    float y = acc * scale + shift;
    y = 0.5f * y * (1.f + erff(y * 0.70710678118654752f));
    unsigned short hi = f2bf(y);
    unsigned short lo = f2bf(y - bf2f(hi));
    size_t rowb = (size_t)(b * 64 + oh * 8 + ow) * 1024;
    out[rowb + ch] = hi;
    out[rowb + 512 + ch] = lo;
  }
}

// ======================= fp32 -> bf16 hi|lo split ==========================
__global__ __launch_bounds__(256) void split_kernel(
    const float* __restrict__ src, unsigned short* __restrict__ dst,
    int kshift, int total4)
{
  int i = blockIdx.x * 256 + threadIdx.x;
  if (i >= total4) return;
  size_t i4 = (size_t)i * 4;
  int K = 1 << kshift;
  int r = (int)(i4 >> kshift);
  int c = (int)(i4 & (size_t)(K - 1));
  float4 xv = *(const float4*)(src + i4);
  unsigned short h0 = f2bf(xv.x), h1 = f2bf(xv.y), h2 = f2bf(xv.z), h3 = f2bf(xv.w);
  unsigned short l0 = f2bf(xv.x - bf2f(h0)), l1 = f2bf(xv.y - bf2f(h1));
  unsigned short l2 = f2bf(xv.z - bf2f(h2)), l3 = f2bf(xv.w - bf2f(h3));
  unsigned short* dr = dst + (size_t)r * (K * 2) + c;
  uint2 hp, lp;
  hp.x = (unsigned)h0 | ((unsigned)h1 << 16);
  hp.y = (unsigned)h2 | ((unsigned)h3 << 16);
  lp.x = (unsigned)l0 | ((unsigned)l1 << 16);
  lp.y = (unsigned)l2 | ((unsigned)l3 << 16);
  *(uint2*)dr = hp;
  *(uint2*)(dr + K) = lp;
}

// ======================= split + row-sum (for linw) ========================
__global__ __launch_bounds__(256) void split_rs_kernel(
    const float* __restrict__ src, unsigned short* __restrict__ dst,
    float* __restrict__ rs, int total4)
{
  int i = blockIdx.x * 256 + threadIdx.x;
  if (i >= total4) return;
  size_t i4 = (size_t)i * 4;
  int r = (int)(i4 >> 11);
  int c = (int)(i4 & 2047);
  float4 xv = *(const float4*)(src + i4);
  unsigned short h0 = f2bf(xv.x), h1 = f2bf(xv.y), h2 = f2bf(xv.z), h3 = f2bf(xv.w);
  unsigned short l0 = f2bf(xv.x - bf2f(h0)), l1 = f2bf(xv.y - bf2f(h1));
  unsigned short l2 = f2bf(xv.z - bf2f(h2)), l3 = f2bf(xv.w - bf2f(h3));
  unsigned short* dr = dst + (size_t)r * 4096 + c;
  uint2 hp, lp;
  hp.x = (unsigned)h0 | ((unsigned)h1 << 16);
  hp.y = (unsigned)h2 | ((unsigned)h3 << 16);
  lp.x = (unsigned)l0 | ((unsigned)l1 << 16);
  lp.y = (unsigned)l2 | ((unsigned)l3 << 16);
  *(uint2*)dr = hp;
  *(uint2*)(dr + 2048) = lp;
  // all 64 lanes of a wave lie in the same row r (waves 256-elem aligned)
  float s = xv.x + xv.y + xv.z + xv.w;
#pragma unroll
  for (int off = 1; off < 64; off <<= 1) s += __shfl_xor(s, off, 64);
  if ((threadIdx.x & 63) == 0) atomicAdd(&rs[r], s);
}

// ======================= pointwise: bf16-split MFMA NT GEMM (batched z=3) ==
__global__ __launch_bounds__(256) void gemm_split_kernel(
    const unsigned short* __restrict__ Aall, const unsigned short* __restrict__ Ball,
    unsigned short* __restrict__ Call, int M, int N, int K)
{
  __shared__ unsigned short sA[4096];    // [64][64]
  __shared__ unsigned short sB[8192];    // [128][64]
  const int t = threadIdx.x;
  const int z = blockIdx.z;
  const unsigned short* A = Aall + (size_t)z * 524288;
  const unsigned short* B = Ball + (size_t)z * 4194304;
  unsigned short* Cq = Call + (size_t)z * 4194304;
  const int m0 = blockIdx.y * 64, n0 = blockIdx.x * 128;
  const int Kp = 3 * K, twoK = 2 * K, Km = K - 1;
  const int lane = t & 63;
  const int wv = t >> 6;
  const int colbase = wv * 32;
  const int h = lane & 15, g = lane >> 4;

  f32x4 acc[4][2];
#pragma unroll
  for (int mf = 0; mf < 4; ++mf)
#pragma unroll
    for (int nf = 0; nf < 2; ++nf)
      acc[mf][nf] = (f32x4){0.f, 0.f, 0.f, 0.f};

  int srow[4], sblk[4];
#pragma unroll
  for (int it = 0; it < 4; ++it) {
    int s = it * 256 + t;
    srow[it] = s >> 3;
    sblk[it] = (s & 7) ^ (srow[it] & 7);
  }
  const int ldsw = (t & 192) << 4;

  for (int k0 = 0; k0 < Kp; k0 += 64) {
    __syncthreads();
#pragma unroll
    for (int it = 0; it < 2; ++it) {
      int kp = k0 + sblk[it] * 8;
      int ac = (kp < twoK) ? (kp & Km) : (kp - K);
      const unsigned short* ga = A + (size_t)(m0 + srow[it]) * twoK + ac;
      __builtin_amdgcn_global_load_lds((gas_t)(const void*)ga,
          (las_t)(void*)((char*)sA + (it * 4096 + ldsw)), 16, 0, 0);
    }
#pragma unroll
    for (int it = 0; it < 4; ++it) {
      int kp = k0 + sblk[it] * 8;
      int bc = (kp < twoK) ? kp : (kp - twoK);
      const unsigned short* gb = B + (size_t)(n0 + srow[it]) * twoK + bc;
      __builtin_amdgcn_global_load_lds((gas_t)(const void*)gb,
          (las_t)(void*)((char*)sB + (it * 4096 + ldsw)), 16, 0, 0);
    }
    __syncthreads();

#pragma unroll
    for (int kk = 0; kk < 2; ++kk) {
      s16x8 af[4], bfr[2];
#pragma unroll
      for (int mf = 0; mf < 4; ++mf) {
        int arow = mf * 16 + h;
        int aoff = arow * 128 + (((kk * 4 + g) ^ (h & 7)) << 4);
        af[mf] = *(const s16x8*)((const char*)sA + aoff);
      }
#pragma unroll
      for (int nf = 0; nf < 2; ++nf) {
        int brow = colbase + nf * 16 + h;
        int boff = brow * 128 + (((kk * 4 + g) ^ (h & 7)) << 4);
        bfr[nf] = *(const s16x8*)((const char*)sB + boff);
      }
#pragma unroll
      for (int mf = 0; mf < 4; ++mf)
#pragma unroll
        for (int nf = 0; nf < 2; ++nf)
          acc[mf][nf] = __builtin_amdgcn_mfma_f32_16x16x32_bf16(
              af[mf], bfr[nf], acc[mf][nf], 0, 0, 0);
    }
  }

  if (z < 2) {
    // Q'/K' layout: rows = attention row index (ch%256), cols = d hi|lo
#pragma unroll
    for (int mf = 0; mf < 4; ++mf) {
      int mbase = m0 + mf * 16 + g * 4;
#pragma unroll
      for (int nf = 0; nf < 2; ++nf) {
        int n = n0 + colbase + nf * 16 + h;
        int bb = n >> 6, d = n & 63;
#pragma unroll
        for (int qq = 0; qq < 4; ++qq) {
          int m = mbase + qq;
          int cc = m >> 8;
          size_t rowb = ((size_t)(bb * 2 + cc) * 256 + (m & 255)) * 128;
          float vvv = acc[mf][nf][qq];
          unsigned short hi = f2bf(vvv);
          unsigned short lo = f2bf(vvv - bf2f(hi));
          Cq[rowb + d] = hi;
          Cq[rowb + 64 + d] = lo;
        }
      }
    }
  } else {
    // V^T layout: rows = d, cols = j hi|lo
#pragma unroll
    for (int mf = 0; mf < 4; ++mf) {
      int mbase = m0 + mf * 16 + g * 4;
      int cc = mbase >> 8;
      int mc = mbase & 255;
#pragma unroll
      for (int nf = 0; nf < 2; ++nf) {
        int n = n0 + colbase + nf * 16 + h;
        int bb = n >> 6, d = n & 63;
        size_t rowb = ((size_t)(bb * 2 + cc) * 64 + d) * 512;
        ushort4 hv, lv;
        float v0 = acc[mf][nf][0], v1 = acc[mf][nf][1];
        float v2 = acc[mf][nf][2], v3 = acc[mf][nf][3];
        hv.x = f2bf(v0); hv.y = f2bf(v1); hv.z = f2bf(v2); hv.w = f2bf(v3);
        lv.x = f2bf(v0 - bf2f(hv.x)); lv.y = f2bf(v1 - bf2f(hv.y));
        lv.z = f2bf(v2 - bf2f(hv.z)); lv.w = f2bf(v3 - bf2f(hv.w));
        *(ushort4*)&Cq[rowb + mc] = hv;
        *(ushort4*)&Cq[rowb + 256 + mc] = lv;
      }
    }
  }
}

// ======================= final GEMM: G = X' * lwp^T (pipelined) ============
// BM=64, BN=128, BK=64, 4 waves (1x4), 3 LDS buffers (72 KB -> 2 blocks/CU),
// counted vmcnt(6). Grid (32,16) ONLY (hardcoded swizzle).
// XCD swizzle: each XCD owns 4 n-tiles x ALL 16 m-tiles -> its B working set
// is 4x128x4096x2B = 4 MB = one XCD L2; B fetched ~once per XCD.
__global__ __launch_bounds__(256, 2) void gemm_final_kernel(
    const unsigned short* __restrict__ A, const unsigned short* __restrict__ B,
    float* __restrict__ C, int M, int N, int K)
{
  __shared__ unsigned short lds[36864];    // 73728 B = 3 x 24576
  const int t = threadIdx.x;

  const int flat = blockIdx.y * 32 + blockIdx.x;
  const int xcd = flat & 7;
  const int ii = flat >> 3;                 // 0..63 within XCD
  const int n0 = (xcd * 4 + (ii & 3)) * 128;
  const int m0 = (ii >> 2) * 64;

  const int twoK = 2 * K, Km = K - 1;
  const int nt = (3 * K) >> 6;             // 96 K-tiles

  const int lane = t & 63;
  const int wv = t >> 6;
  const int colbase = wv * 32;
  const int h = lane & 15, g = lane >> 4;

  f32x4 acc[4][2];
#pragma unroll
  for (int mf = 0; mf < 4; ++mf)
#pragma unroll
    for (int nf = 0; nf < 2; ++nf)
      acc[mf][nf] = (f32x4){0.f, 0.f, 0.f, 0.f};

  int arow[2], ablk[2], brow[4], bblk[4];
#pragma unroll
  for (int it = 0; it < 2; ++it) {
    int s = it * 256 + t;
    arow[it] = s >> 3;
    ablk[it] = (s & 7) ^ (arow[it] & 7);
  }
#pragma unroll
  for (int it = 0; it < 4; ++it) {
    int s = it * 256 + t;
    brow[it] = s >> 3;
    bblk[it] = (s & 7) ^ (brow[it] & 7);
  }

  auto issueA = [&](int buf, int tt, int it) {
    int kp = tt * 64 + ablk[it] * 8;
    int ac = (kp < twoK) ? (kp & Km) : (kp - K);
    __builtin_amdgcn_global_load_lds(
        (gas_t)(const void*)(A + (size_t)(m0 + arow[it]) * twoK + ac),
        (las_t)(void*)((char*)lds + (buf * 24576 + it * 4096 + t * 16)), 16, 0, 0);
  };
  auto issueB = [&](int buf, int tt, int it) {
    int kp = tt * 64 + bblk[it] * 8;
    int bc = (kp < twoK) ? kp : (kp - twoK);
    __builtin_amdgcn_global_load_lds(
        (gas_t)(const void*)(B + (size_t)(n0 + brow[it]) * twoK + bc),
        (las_t)(void*)((char*)lds + (buf * 24576 + 8192 + it * 4096 + t * 16)), 16, 0, 0);
  };

  int colx[2];
  colx[0] = ((g) ^ (h & 7)) << 4;
  colx[1] = ((4 + g) ^ (h & 7)) << 4;

  auto rdA = [&](int buf, int kk, int mf) -> s16x8 {
    return *(const s16x8*)((const char*)lds +
        (buf * 24576 + (mf * 16 + h) * 128 + colx[kk]));
  };
  auto rdB = [&](int buf, int kk, int nf) -> s16x8 {
    return *(const s16x8*)((const char*)lds +
        (buf * 24576 + 8192 + (colbase + nf * 16 + h) * 128 + colx[kk]));
  };

#define MFMA8(A0, A1, A2, A3, B0, B1) \
  acc[0][0] = __builtin_amdgcn_mfma_f32_16x16x32_bf16(A0, B0, acc[0][0], 0, 0, 0); \
  acc[1][0] = __builtin_amdgcn_mfma_f32_16x16x32_bf16(A1, B0, acc[1][0], 0, 0, 0); \
  acc[2][0] = __builtin_amdgcn_mfma_f32_16x16x32_bf16(A2, B0, acc[2][0], 0, 0, 0); \
  acc[3][0] = __builtin_amdgcn_mfma_f32_16x16x32_bf16(A3, B0, acc[3][0], 0, 0, 0); \
  acc[0][1] = __builtin_amdgcn_mfma_f32_16x16x32_bf16(A0, B1, acc[0][1], 0, 0, 0); \
  acc[1][1] = __builtin_amdgcn_mfma_f32_16x16x32_bf16(A1, B1, acc[1][1], 0, 0, 0); \
  acc[2][1] = __builtin_amdgcn_mfma_f32_16x16x32_bf16(A2, B1, acc[2][1], 0, 0, 0); \
  acc[3][1] = __builtin_amdgcn_mfma_f32_16x16x32_bf16(A3, B1, acc[3][1], 0, 0, 0);

  // ---- prologue: stage tiles 0 and 1 (6 loads each) ----
#pragma unroll
  for (int it = 0; it < 2; ++it) issueA(0, 0, it);
#pragma unroll
  for (int it = 0; it < 4; ++it) issueB(0, 0, it);
#pragma unroll
  for (int it = 0; it < 2; ++it) issueA(1, 1, it);
#pragma unroll
  for (int it = 0; it < 4; ++it) issueB(1, 1, it);
  asm volatile("s_waitcnt vmcnt(6)" ::: "memory");
  __builtin_amdgcn_sched_barrier(0);
  __builtin_amdgcn_s_barrier();
  __builtin_amdgcn_sched_barrier(0);

  int bR = 0;
  for (int tt = 0; tt <= nt - 3; ++tt) {
    const int bn2 = (bR >= 1) ? bR - 1 : 2;      // (bR+2)%3
    // ---- phase 0 (kk=0): 6 ds_read; prefetch A0,A1,B0 ----
    s16x8 a0 = rdA(bR, 0, 0), a1 = rdA(bR, 0, 1), a2 = rdA(bR, 0, 2), a3 = rdA(bR, 0, 3);
    s16x8 b0 = rdB(bR, 0, 0), b1 = rdB(bR, 0, 1);
    issueA(bn2, tt + 2, 0); issueA(bn2, tt + 2, 1); issueB(bn2, tt + 2, 0);
    __builtin_amdgcn_s_barrier();
    __builtin_amdgcn_s_setprio(1);
    MFMA8(a0, a1, a2, a3, b0, b1)
    __builtin_amdgcn_s_setprio(0);
    __builtin_amdgcn_s_barrier();
    // ---- phase 1 (kk=1): 6 ds_read; prefetch B1..B3; counted vmcnt ----
    a0 = rdA(bR, 1, 0); a1 = rdA(bR, 1, 1); a2 = rdA(bR, 1, 2); a3 = rdA(bR, 1, 3);
    b0 = rdB(bR, 1, 0); b1 = rdB(bR, 1, 1);
    issueB(bn2, tt + 2, 1); issueB(bn2, tt + 2, 2); issueB(bn2, tt + 2, 3);
    __builtin_amdgcn_s_barrier();
    __builtin_amdgcn_s_setprio(1);
    MFMA8(a0, a1, a2, a3, b0, b1)
    __builtin_amdgcn_s_setprio(0);
    asm volatile("s_waitcnt vmcnt(6)" ::: "memory");
    __builtin_amdgcn_sched_barrier(0);
    __builtin_amdgcn_s_barrier();
    __builtin_amdgcn_sched_barrier(0);
    bR = (bR == 2) ? 0 : bR + 1;
  }

  auto compute_tile = [&](int buf) {
#pragma unroll
    for (int kk = 0; kk < 2; ++kk) {
      s16x8 ta0 = rdA(buf, kk, 0), ta1 = rdA(buf, kk, 1);
      s16x8 ta2 = rdA(buf, kk, 2), ta3 = rdA(buf, kk, 3);
      s16x8 tb0 = rdB(buf, kk, 0), tb1 = rdB(buf, kk, 1);
      MFMA8(ta0, ta1, ta2, ta3, tb0, tb1)
    }
  };
  compute_tile(bR);
  __syncthreads();
  compute_tile((bR == 2) ? 0 : bR + 1);
#undef MFMA8

#pragma unroll
  for (int mf = 0; mf < 4; ++mf) {
    int mbase = m0 + mf * 16 + g * 4;
#pragma unroll
    for (int nf = 0; nf < 2; ++nf) {
      int n = n0 + colbase + nf * 16 + h;
#pragma unroll
      for (int qq = 0; qq < 4; ++qq)
        C[(size_t)(mbase + qq) * N + n] = acc[mf][nf][qq];
    }
  }
}

// ======================= Attention (MFMA, split bf16) ======================
// Writes O directly as X' split-bf16 [1024][4096] (GEMM-A layout):
//   Xrow = b*16 + cc*8 + (d>>3), Xcol = dd*8 + (d&7), lo at +2048.
__global__ __launch_bounds__(256) void attn_mfma_kernel(
    const unsigned short* __restrict__ qp, const unsigned short* __restrict__ kp,
    const unsigned short* __restrict__ vtp, const float* __restrict__ pos,
    unsigned short* __restrict__ Xp)
{
  __shared__ char smem[59904];
  unsigned short* qs = (unsigned short*)smem;
  unsigned short* kv = (unsigned short*)(smem + 8704);
  float* sc = (float*)(smem + 26112);
  unsigned short* ps = (unsigned short*)(smem + 26112);

  const int t = threadIdx.x;
  const int rt = blockIdx.x, cc = blockIdx.y, b = blockIdx.z;
  const int i0 = rt * 32;
  const size_t qkbase = (size_t)(b * 2 + cc) * 256;
  const size_t vbase  = (size_t)(b * 2 + cc) * 64;

  const int lane = t & 63, wvv = t >> 6;
  const int h = lane & 15, g = lane >> 4;

  // ---- stage Q tile (32 rows x 128 split cols = 512 int4) ----
#pragma unroll
  for (int rep = 0; rep < 2; ++rep) {
    int s = t + rep * 256;
    int row = s >> 4;
    int blk = s & 15;
    int4 val = *(const int4*)(qp + (qkbase + i0 + row) * 128 + blk * 8);
    *(int4*)((char*)qs + row * 272 + blk * 16) = val;
  }

  // ---- S phase: 4 chunks of 64 cols ----
  for (int c = 0; c < 4; ++c) {
    __syncthreads();
#pragma unroll
    for (int p2 = 0; p2 < 4; ++p2) {
      int s = t + p2 * 256;
      int row = s >> 4;
      int blk = s & 15;
      int4 val = *(const int4*)(kp + (qkbase + c * 64 + row) * 128 + blk * 8);
      *(int4*)((char*)kv + row * 272 + blk * 16) = val;
    }
    __syncthreads();
    f32x4 acc2[2];
    acc2[0] = (f32x4){0.f, 0.f, 0.f, 0.f};
    acc2[1] = (f32x4){0.f, 0.f, 0.f, 0.f};
#pragma unroll
    for (int kk = 0; kk < 6; ++kk) {
      int abase = (kk < 2) ? kk * 32 : (kk < 4) ? 64 + (kk - 2) * 32 : (kk - 4) * 32;
      int bbase = (kk < 2) ? kk * 32 : (kk < 4) ? (kk - 2) * 32 : 64 + (kk - 4) * 32;
      s16x8 bfrag = *(const s16x8*)((char*)kv + (wvv * 16 + h) * 272 + (bbase + g * 8) * 2);
#pragma unroll
      for (int mf = 0; mf < 2; ++mf) {
        s16x8 afrag = *(const s16x8*)((char*)qs + (mf * 16 + h) * 272 + (abase + g * 8) * 2);
        acc2[mf] = __builtin_amdgcn_mfma_f32_16x16x32_bf16(afrag, bfrag, acc2[mf], 0, 0, 0);
      }
    }
#pragma unroll
    for (int mf = 0; mf < 2; ++mf)
#pragma unroll
      for (int qq = 0; qq < 4; ++qq) {
        int row = mf * 16 + g * 4 + qq;
        int j = c * 64 + wvv * 16 + h;
        sc[row * 264 + j] = acc2[mf][qq] * 0.125f +
            pos[((size_t)cc * 256 + i0 + row) * 256 + j];
      }
  }
  __syncthreads();

  // ---- softmax + in-place P split-bf16 ----
  {
    const int r = t >> 3, j8 = t & 7;
    float e[32];
    float mx = -3.4e38f;
#pragma unroll
    for (int jj = 0; jj < 32; ++jj) {
      e[jj] = sc[r * 264 + j8 + 8 * jj];
      mx = fmaxf(mx, e[jj]);
    }
#pragma unroll
    for (int mset = 1; mset < 8; mset <<= 1) mx = fmaxf(mx, __shfl_xor(mx, mset, 64));
    float sum = 0.f;
#pragma unroll
    for (int jj = 0; jj < 32; ++jj) {
      e[jj] = expf(e[jj] - mx);
      sum += e[jj];
    }
#pragma unroll
    for (int mset = 1; mset < 8; mset <<= 1) sum += __shfl_xor(sum, mset, 64);
    float inv = 1.f / sum;
    __syncthreads();
#pragma unroll
    for (int jj = 0; jj < 32; ++jj) {
      float pv = e[jj] * inv;
      unsigned short hi = f2bf(pv);
      unsigned short lo = f2bf(pv - bf2f(hi));
      int j = j8 + 8 * jj;
      ps[r * 528 + j] = hi;
      ps[r * 528 + 264 + j] = lo;
    }
  }

  // ---- PV ----
  f32x4 oacc[2];
  oacc[0] = (f32x4){0.f, 0.f, 0.f, 0.f};
  oacc[1] = (f32x4){0.f, 0.f, 0.f, 0.f};
  for (int c = 0; c < 4; ++c) {
    __syncthreads();
#pragma unroll
    for (int p2 = 0; p2 < 4; ++p2) {
      int s = t + p2 * 256, row = s >> 4, blk = s & 15;
      int col = (blk < 8) ? (c * 64 + blk * 8) : (256 + c * 64 + (blk - 8) * 8);
      int4 val = *(const int4*)(vtp + (vbase + row) * 512 + col);
      *(int4*)((char*)kv + row * 272 + blk * 16) = val;
    }
    __syncthreads();
#pragma unroll
    for (int kk = 0; kk < 6; ++kk) {
      int abase = (kk < 2) ? (c * 64 + kk * 32)
                : (kk < 4) ? (264 + c * 64 + (kk - 2) * 32)
                           : (c * 64 + (kk - 4) * 32);
      int bbase = (kk < 2) ? kk * 32 : (kk < 4) ? (kk - 2) * 32 : 64 + (kk - 4) * 32;
      s16x8 bfrag = *(const s16x8*)((char*)kv + (wvv * 16 + h) * 272 + (bbase + g * 8) * 2);
#pragma unroll
      for (int mf = 0; mf < 2; ++mf) {
        s16x8 afrag = *(const s16x8*)((char*)ps + (mf * 16 + h) * 1056 + (abase + g * 8) * 2);
        oacc[mf] = __builtin_amdgcn_mfma_f32_16x16x32_bf16(afrag, bfrag, oacc[mf], 0, 0, 0);
      }
    }
  }
  // ---- write O as X' split-bf16 ----
  {
    int Xrow = b * 16 + cc * 8 + wvv * 2 + (h >> 3);
    int c7 = h & 7;
#pragma unroll
    for (int mf = 0; mf < 2; ++mf)
#pragma unroll
      for (int qq = 0; qq < 4; ++qq) {
        int dd = i0 + mf * 16 + g * 4 + qq;
        float vvv = oacc[mf][qq];
        unsigned short hi = f2bf(vvv);
        unsigned short lo = f2bf(vvv - bf2f(hi));
        size_t base = (size_t)Xrow * 4096 + dd * 8 + c7;
        Xp[base] = hi;
        Xp[base + 2048] = lo;
      }
  }
}

// ======================= epilogue: out = c1w*G + c1b*rs + lin_b ===========
__global__ __launch_bounds__(256) void epilogue_kernel(
    const float* __restrict__ G, const float* __restrict__ rs,
    const float* __restrict__ c1w, const float* __restrict__ c1b,
    const float* __restrict__ linb, float* __restrict__ out)
{
  __shared__ float W[512];
  __shared__ float Bp[32];
  const int t = threadIdx.x;
  const int ntile = blockIdx.x;   // 0..15
  const int b = blockIdx.y;       // 0..63
  W[t] = c1w[t];                  // 256 threads: stage 2 elements each
  W[t + 256] = c1w[t + 256];
  if (t < 32) Bp[t] = c1b[t];
  __syncthreads();
  const int n = ntile * 256 + t;
  float gv[16];
#pragma unroll
  for (int ch = 0; ch < 16; ++ch)
    gv[ch] = G[(size_t)(b * 16 + ch) * 4096 + n];
  const float rsn = rs[n];
  const float lbn = linb[n];
#pragma unroll
  for (int o = 0; o < 32; ++o) {
    float s = lbn + Bp[o] * rsn;
#pragma unroll
    for (int ch = 0; ch < 16; ++ch) s = fmaf(W[o * 16 + ch], gv[ch], s);
    out[(size_t)(b * 32 + o) * 4096 + n] = s;
  }
}

// ======================= launch ============================================
extern "C" void kernel_launch(void* const* d_in, const int* in_sizes, int n_in,
                              void* d_out, int out_size, void* d_ws, size_t ws_size,
                              hipStream_t stream) {
  const float* q    = (const float*)d_in[0];
  const float* k    = (const float*)d_in[1];
  const float* v    = (const float*)d_in[2];
  const float* dwk  = (const float*)d_in[3];
  const float* bng  = (const float*)d_in[4];
  const float* bnb  = (const float*)d_in[5];
  const float* bnm  = (const float*)d_in[6];
  const float* bnv  = (const float*)d_in[7];
  const float* pwk  = (const float*)d_in[8];
  const float* pos  = (const float*)d_in[9];
  const float* c1w  = (const float*)d_in[10];
  const float* c1b  = (const float*)d_in[11];
  const float* linw = (const float*)d_in[12];
  const float* linb = (const float*)d_in[13];
  float* out = (float*)d_out;

  if (ws_size < 50331648u) return;

  char* ws = (char*)d_ws;
  unsigned short* qp   = (unsigned short*)(ws + 0);          //  8,388,608
  unsigned short* kpp  = (unsigned short*)(ws + 8388608);    //  8,388,608
  unsigned short* vtp  = (unsigned short*)(ws + 16777216);   //  8,388,608
  unsigned short* tTp  = (unsigned short*)(ws + 25165824);   // 25,165,824
  unsigned short* pwkp = (unsigned short*)d_out;             //  3,145,728 (d_out scratch)
  unsigned short* Xp   = (unsigned short*)(ws + 25165824);   //  8,388,608 (over tTp)
  float*          rs   = (float*)(ws + 0);                   //     16,384 (over qp)
  unsigned short* lwp  = (unsigned short*)d_out;             // 33,554,432 (d_out scratch)
  float*          G    = (float*)(ws + 33554432);            // 16,777,216

  // 1) split pointwise weights (into d_out scratch)
  split_kernel<<<768, 256, 0, stream>>>(pwk, pwkp, 9, 196608);

  // 2) dwconv+BN+GELU, all three inputs
  stageA_kernel<<<dim3(1024, 3), 256, 0, stream>>>(
      q, k, v, dwk, bng, bnb, bnm, bnv, tTp);

  // 3) pointwise GEMMs -> qp/kpp/vtp
  gemm_split_kernel<<<dim3(32, 8, 3), 256, 0, stream>>>(
      pwkp, tTp, qp, 512, 4096, 512);

  // 4) attention -> X' split-bf16 (GEMM-A layout)
  attn_mfma_kernel<<<dim3(8, 2, 64), 256, 0, stream>>>(qp, kpp, vtp, pos, Xp);

  // 5) split linw (+ row sums) into d_out scratch / ws
  hipMemsetAsync(rs, 0, 16384, stream);
  split_rs_kernel<<<8192, 256, 0, stream>>>(linw, lwp, rs, 2097152);

  // 6) G = X' * lwp^T   (M=1024, N=4096, K=2048 split)
  gemm_final_kernel<<<dim3(32, 16), 256, 0, stream>>>(Xp, lwp, G, 1024, 4096, 2048);

  // 7) out = c1w*G + c1b*rs + lin_b   (overwrites d_out)
  epilogue_kernel<<<dim3(16, 64), 256, 0, stream>>>(G, rs, c1w, c1b, linb, out);
}